// Round 1
// baseline (1405.807 us; speedup 1.0000x reference)
//
#include <hip/hip_runtime.h>
#include <hip/hip_bf16.h>

// Problem constants (B=2, S=4096 -> T=8192 tokens)
#define TT 8192
#define DD 1024
#define HH 2048
#define EE 8

typedef __bf16 bf16x8 __attribute__((ext_vector_type(8)));
typedef float floatx4 __attribute__((ext_vector_type(4)));

// float -> bf16 bits, round-to-nearest-even
__device__ __forceinline__ short f2bf(float f) {
  unsigned u = __float_as_uint(f);
  u += 0x7fffu + ((u >> 16) & 1u);
  return (short)(u >> 16);
}

// ---------------- Router: logits, top-2, softmax, expert lists ----------------
__global__ __launch_bounds__(256) void router_kernel(
    const float* __restrict__ x, const float* __restrict__ rw,
    int* __restrict__ counts, float* __restrict__ P_sum,
    int* __restrict__ list_token, float* __restrict__ list_coef)
{
  __shared__ float P_loc[EE];
  const int tid = threadIdx.x;
  if (tid < EE) P_loc[tid] = 0.f;
  __syncthreads();
  const int lane = tid & 63;
  const int wid = blockIdx.x * 4 + (tid >> 6);   // 0..2047 waves
  for (int ti = 0; ti < 4; ++ti) {
    const int t = wid * 4 + ti;                  // token id
    float s[EE];
#pragma unroll
    for (int e = 0; e < EE; ++e) s[e] = 0.f;
    const float4* xp = (const float4*)(x + (size_t)t * DD);
#pragma unroll
    for (int j = 0; j < 4; ++j) {
      float4 xv = xp[j * 64 + lane];
#pragma unroll
      for (int e = 0; e < EE; ++e) {
        const float4* rp = (const float4*)(rw + e * DD);
        float4 rv = rp[j * 64 + lane];
        s[e] += xv.x * rv.x + xv.y * rv.y + xv.z * rv.z + xv.w * rv.w;
      }
    }
#pragma unroll
    for (int off = 32; off > 0; off >>= 1)
#pragma unroll
      for (int e = 0; e < EE; ++e)
        s[e] += __shfl_down(s[e], off);
    if (lane == 0) {
      // top-2 (ties -> lower index, matching jax.lax.top_k)
      int i0 = 0; float l0 = s[0];
      for (int e = 1; e < EE; ++e) if (s[e] > l0) { l0 = s[e]; i0 = e; }
      int i1 = -1; float l1 = -3.4e38f;
      for (int e = 0; e < EE; ++e) if (e != i0 && s[e] > l1) { l1 = s[e]; i1 = e; }
      const float g0 = 1.f / (1.f + __expf(l1 - l0));  // softmax over {l0,l1}
      const float g1 = 1.f - g0;
      // full softmax for aux loss (l0 is the max)
      float pr[EE]; float sum = 0.f;
      for (int e = 0; e < EE; ++e) { pr[e] = __expf(s[e] - l0); sum += pr[e]; }
      const float inv = 1.f / sum;
      for (int e = 0; e < EE; ++e) atomicAdd(&P_loc[e], pr[e] * inv);
      int p0 = atomicAdd(&counts[i0], 1);
      list_token[i0 * TT + p0] = t; list_coef[i0 * TT + p0] = g0;
      int p1 = atomicAdd(&counts[i1], 1);
      list_token[i1 * TT + p1] = t; list_coef[i1 * TT + p1] = g1;
    }
  }
  __syncthreads();
  if (tid < EE) atomicAdd(&P_sum[tid], P_loc[tid]);
}

// ---------------- Aux loss + prefix-sum offsets ----------------
__global__ void aux_kernel(const int* __restrict__ counts, const float* __restrict__ P_sum,
                           int* __restrict__ offsets, float* __restrict__ out_aux)
{
  if (threadIdx.x == 0) {
    float aux = 0.f; int off = 0;
    for (int e = 0; e < EE; ++e) {
      aux += ((float)counts[e] / (float)TT) * (P_sum[e] / (float)TT);
      offsets[e] = off; off += counts[e];
    }
    *out_aux = aux * (float)EE;
  }
}

// ---------------- G1: H = silu(Xg @ w1[e]) * (Xg @ w3[e]) -> Hbuf (bf16) ----------------
// grid: (HH/128, TT/128, EE); block 256 (4 waves, 2x2)
__global__ __launch_bounds__(256, 2) void g1_kernel(
    const float* __restrict__ x, const float* __restrict__ w1, const float* __restrict__ w3,
    const int* __restrict__ counts, const int* __restrict__ offsets,
    const int* __restrict__ list_token, short* __restrict__ Hbuf)
{
  const int e = blockIdx.z, rb = blockIdx.y, nb = blockIdx.x;
  const int cnt = counts[e];
  if (rb * 128 >= cnt) return;
  __shared__ short Asm[128 * 40];
  __shared__ short B1sm[128 * 40];
  __shared__ short B3sm[128 * 40];
  const int tid = threadIdx.x, lane = tid & 63, wv = tid >> 6;
  const int wm = (wv >> 1) * 64, wn = (wv & 1) * 64;
  const int quad = lane >> 4, l16 = lane & 15;
  floatx4 acc1[4][4] = {{{0.f}}};
  floatx4 acc3[4][4] = {{{0.f}}};
  const int ar = tid >> 3, ak = (tid & 7) * 4;      // A staging: row, k4
  const int bn = (tid & 31) * 4, bk = tid >> 5;     // B staging: n4, k
  int tok[4];
#pragma unroll
  for (int i = 0; i < 4; ++i) {
    int gr = rb * 128 + ar + 32 * i;
    tok[i] = (gr < cnt) ? list_token[e * TT + gr] : list_token[e * TT];
  }
  const float* w1e = w1 + (size_t)e * DD * HH + (size_t)nb * 128;
  const float* w3e = w3 + (size_t)e * DD * HH + (size_t)nb * 128;

  for (int k0 = 0; k0 < DD; k0 += 32) {
    __syncthreads();
    // A tile [128 x 32] fp32->bf16, row-major stride 40
#pragma unroll
    for (int i = 0; i < 4; ++i) {
      int r = ar + 32 * i;
      float4 v = *(const float4*)(x + (size_t)tok[i] * DD + k0 + ak);
      short4 sv = make_short4(f2bf(v.x), f2bf(v.y), f2bf(v.z), f2bf(v.w));
      *(short4*)&Asm[r * 40 + ak] = sv;
    }
    // B tiles [32 x 128] fp32->bf16, stored TRANSPOSED [n][k] stride 40
#pragma unroll
    for (int i = 0; i < 4; ++i) {
      int kk = bk + 8 * i;
      float4 v1 = *(const float4*)(w1e + (size_t)(k0 + kk) * HH + bn);
      float4 v3 = *(const float4*)(w3e + (size_t)(k0 + kk) * HH + bn);
      B1sm[(bn + 0) * 40 + kk] = f2bf(v1.x);
      B1sm[(bn + 1) * 40 + kk] = f2bf(v1.y);
      B1sm[(bn + 2) * 40 + kk] = f2bf(v1.z);
      B1sm[(bn + 3) * 40 + kk] = f2bf(v1.w);
      B3sm[(bn + 0) * 40 + kk] = f2bf(v3.x);
      B3sm[(bn + 1) * 40 + kk] = f2bf(v3.y);
      B3sm[(bn + 2) * 40 + kk] = f2bf(v3.z);
      B3sm[(bn + 3) * 40 + kk] = f2bf(v3.w);
    }
    __syncthreads();
    bf16x8 af[4], b1f[4], b3f[4];
#pragma unroll
    for (int mi = 0; mi < 4; ++mi)
      af[mi] = *(const bf16x8*)&Asm[(wm + mi * 16 + l16) * 40 + quad * 8];
#pragma unroll
    for (int ni = 0; ni < 4; ++ni) {
      b1f[ni] = *(const bf16x8*)&B1sm[(wn + ni * 16 + l16) * 40 + quad * 8];
      b3f[ni] = *(const bf16x8*)&B3sm[(wn + ni * 16 + l16) * 40 + quad * 8];
    }
#pragma unroll
    for (int mi = 0; mi < 4; ++mi)
#pragma unroll
      for (int ni = 0; ni < 4; ++ni) {
        acc1[mi][ni] = __builtin_amdgcn_mfma_f32_16x16x32_bf16(af[mi], b1f[ni], acc1[mi][ni], 0, 0, 0);
        acc3[mi][ni] = __builtin_amdgcn_mfma_f32_16x16x32_bf16(af[mi], b3f[ni], acc3[mi][ni], 0, 0, 0);
      }
  }
  // epilogue: SwiGLU, store bf16 H rows
  const int off = offsets[e];
#pragma unroll
  for (int mi = 0; mi < 4; ++mi)
#pragma unroll
    for (int r = 0; r < 4; ++r) {
      int row = wm + mi * 16 + quad * 4 + r;
      int grow = rb * 128 + row;
      if (grow < cnt) {
        size_t rowbase = (size_t)(off + grow) * HH + (size_t)nb * 128 + wn;
#pragma unroll
        for (int ni = 0; ni < 4; ++ni) {
          float a = acc1[mi][ni][r], b = acc3[mi][ni][r];
          float h = a / (1.f + __expf(-a)) * b;   // silu(a) * b
          Hbuf[rowbase + ni * 16 + l16] = f2bf(h);
        }
      }
    }
}

// ---------------- G2: out[token] += coef * (Hrows @ w2[e]) ----------------
// grid: (DD/128, TT/128, EE); block 256
__global__ __launch_bounds__(256, 2) void g2_kernel(
    const short* __restrict__ Hbuf, const float* __restrict__ w2,
    const int* __restrict__ counts, const int* __restrict__ offsets,
    const int* __restrict__ list_token, const float* __restrict__ list_coef,
    float* __restrict__ out)
{
  const int e = blockIdx.z, rb = blockIdx.y, nb = blockIdx.x;
  const int cnt = counts[e];
  if (rb * 128 >= cnt) return;
  __shared__ short Asm[128 * 40];
  __shared__ short Bsm[128 * 40];
  const int tid = threadIdx.x, lane = tid & 63, wv = tid >> 6;
  const int wm = (wv >> 1) * 64, wn = (wv & 1) * 64;
  const int quad = lane >> 4, l16 = lane & 15;
  floatx4 acc[4][4] = {{{0.f}}};
  const int ar = tid >> 3, ak = (tid & 7) * 4;
  const int bn = (tid & 31) * 4, bk = tid >> 5;
  const int off = offsets[e];
  size_t hrow[4];
#pragma unroll
  for (int i = 0; i < 4; ++i) {
    int gr = rb * 128 + ar + 32 * i;
    int cg = (gr < cnt) ? gr : (cnt - 1);
    hrow[i] = (size_t)(off + cg) * HH;
  }
  const float* w2e = w2 + (size_t)e * HH * DD + (size_t)nb * 128;

  for (int k0 = 0; k0 < HH; k0 += 32) {
    __syncthreads();
#pragma unroll
    for (int i = 0; i < 4; ++i) {
      int r = ar + 32 * i;
      short4 sv = *(const short4*)(Hbuf + hrow[i] + k0 + ak);
      *(short4*)&Asm[r * 40 + ak] = sv;
    }
#pragma unroll
    for (int i = 0; i < 4; ++i) {
      int kk = bk + 8 * i;
      float4 v = *(const float4*)(w2e + (size_t)(k0 + kk) * DD + bn);
      Bsm[(bn + 0) * 40 + kk] = f2bf(v.x);
      Bsm[(bn + 1) * 40 + kk] = f2bf(v.y);
      Bsm[(bn + 2) * 40 + kk] = f2bf(v.z);
      Bsm[(bn + 3) * 40 + kk] = f2bf(v.w);
    }
    __syncthreads();
    bf16x8 af[4], bf[4];
#pragma unroll
    for (int mi = 0; mi < 4; ++mi)
      af[mi] = *(const bf16x8*)&Asm[(wm + mi * 16 + l16) * 40 + quad * 8];
#pragma unroll
    for (int ni = 0; ni < 4; ++ni)
      bf[ni] = *(const bf16x8*)&Bsm[(wn + ni * 16 + l16) * 40 + quad * 8];
#pragma unroll
    for (int mi = 0; mi < 4; ++mi)
#pragma unroll
      for (int ni = 0; ni < 4; ++ni)
        acc[mi][ni] = __builtin_amdgcn_mfma_f32_16x16x32_bf16(af[mi], bf[ni], acc[mi][ni], 0, 0, 0);
  }
  // epilogue: weighted scatter-add into out rows
#pragma unroll
  for (int mi = 0; mi < 4; ++mi)
#pragma unroll
    for (int r = 0; r < 4; ++r) {
      int row = wm + mi * 16 + quad * 4 + r;
      int grow = rb * 128 + row;
      if (grow < cnt) {
        int tokid = list_token[e * TT + grow];
        float coef = list_coef[e * TT + grow];
        float* orow = out + (size_t)tokid * DD + (size_t)nb * 128 + wn;
#pragma unroll
        for (int ni = 0; ni < 4; ++ni)
          atomicAdd(&orow[ni * 16 + l16], coef * acc[mi][ni][r]);
      }
    }
}

extern "C" void kernel_launch(void* const* d_in, const int* in_sizes, int n_in,
                              void* d_out, int out_size, void* d_ws, size_t ws_size,
                              hipStream_t stream)
{
  const float* x  = (const float*)d_in[0];
  const float* rw = (const float*)d_in[1];
  const float* w1 = (const float*)d_in[2];
  const float* w3 = (const float*)d_in[3];
  const float* w2 = (const float*)d_in[4];
  float* out = (float*)d_out;

  char* ws = (char*)d_ws;
  int*   counts    = (int*)(ws + 0);                       // 8 ints
  float* P_sum     = (float*)(ws + 64);                    // 8 floats
  int*   offsets   = (int*)(ws + 128);                     // 8 ints
  int*   list_tok  = (int*)(ws + 1024);                    // E*T ints   (256 KB)
  float* list_coef = (float*)(ws + 1024 + EE * TT * 4);    // E*T floats (256 KB)
  short* Hbuf      = (short*)(ws + (1 << 20));             // 16384 x 2048 bf16 (64 MB)

  hipMemsetAsync(ws, 0, 128, stream);                                   // counts + P_sum
  hipMemsetAsync(d_out, 0, (size_t)TT * DD * sizeof(float), stream);    // scatter target

  router_kernel<<<512, 256, 0, stream>>>(x, rw, counts, P_sum, list_tok, list_coef);
  aux_kernel<<<1, 64, 0, stream>>>(counts, P_sum, offsets, out + (size_t)TT * DD);
  g1_kernel<<<dim3(HH / 128, TT / 128, EE), 256, 0, stream>>>(x, w1, w3, counts, offsets, list_tok, Hbuf);
  g2_kernel<<<dim3(DD / 128, TT / 128, EE), 256, 0, stream>>>(Hbuf, w2, counts, offsets, list_tok, list_coef, out);
}

// Round 2
// 889.092 us; speedup vs baseline: 1.5812x; 1.5812x over previous
//
#include <hip/hip_runtime.h>
#include <hip/hip_bf16.h>

// Problem constants (B=2, S=4096 -> T=8192 tokens)
#define TT 8192
#define DD 1024
#define HH 2048
#define EE 8

typedef __bf16 bf16x8 __attribute__((ext_vector_type(8)));
typedef float floatx4 __attribute__((ext_vector_type(4)));
typedef short shortx8 __attribute__((ext_vector_type(8)));

// float -> bf16 bits, round-to-nearest-even
__device__ __forceinline__ short f2bf(float f) {
  unsigned u = __float_as_uint(f);
  u += 0x7fffu + ((u >> 16) & 1u);
  return (short)(u >> 16);
}

// ---------------- Router: logits, top-2, softmax, expert lists ----------------
__global__ __launch_bounds__(256) void router_kernel(
    const float* __restrict__ x, const float* __restrict__ rw,
    int* __restrict__ counts, float* __restrict__ P_sum,
    int* __restrict__ list_token, float* __restrict__ list_coef)
{
  __shared__ float P_loc[EE];
  const int tid = threadIdx.x;
  if (tid < EE) P_loc[tid] = 0.f;
  __syncthreads();
  const int lane = tid & 63;
  const int wid = blockIdx.x * 4 + (tid >> 6);   // 0..2047 waves
  for (int ti = 0; ti < 4; ++ti) {
    const int t = wid * 4 + ti;                  // token id
    float s[EE];
#pragma unroll
    for (int e = 0; e < EE; ++e) s[e] = 0.f;
    const float4* xp = (const float4*)(x + (size_t)t * DD);
#pragma unroll
    for (int j = 0; j < 4; ++j) {
      float4 xv = xp[j * 64 + lane];
#pragma unroll
      for (int e = 0; e < EE; ++e) {
        const float4* rp = (const float4*)(rw + e * DD);
        float4 rv = rp[j * 64 + lane];
        s[e] += xv.x * rv.x + xv.y * rv.y + xv.z * rv.z + xv.w * rv.w;
      }
    }
#pragma unroll
    for (int off = 32; off > 0; off >>= 1)
#pragma unroll
      for (int e = 0; e < EE; ++e)
        s[e] += __shfl_down(s[e], off);
    if (lane == 0) {
      // top-2 (ties -> lower index, matching jax.lax.top_k)
      int i0 = 0; float l0 = s[0];
      for (int e = 1; e < EE; ++e) if (s[e] > l0) { l0 = s[e]; i0 = e; }
      int i1 = -1; float l1 = -3.4e38f;
      for (int e = 0; e < EE; ++e) if (e != i0 && s[e] > l1) { l1 = s[e]; i1 = e; }
      const float g0 = 1.f / (1.f + __expf(l1 - l0));  // softmax over {l0,l1}
      const float g1 = 1.f - g0;
      // full softmax for aux loss (l0 is the max)
      float pr[EE]; float sum = 0.f;
      for (int e = 0; e < EE; ++e) { pr[e] = __expf(s[e] - l0); sum += pr[e]; }
      const float inv = 1.f / sum;
      for (int e = 0; e < EE; ++e) atomicAdd(&P_loc[e], pr[e] * inv);
      int p0 = atomicAdd(&counts[i0], 1);
      list_token[i0 * TT + p0] = t; list_coef[i0 * TT + p0] = g0;
      int p1 = atomicAdd(&counts[i1], 1);
      list_token[i1 * TT + p1] = t; list_coef[i1 * TT + p1] = g1;
    }
  }
  __syncthreads();
  if (tid < EE) atomicAdd(&P_sum[tid], P_loc[tid]);
}

// ---------------- Aux loss + prefix-sum offsets ----------------
__global__ void aux_kernel(const int* __restrict__ counts, const float* __restrict__ P_sum,
                           int* __restrict__ offsets, float* __restrict__ out_aux)
{
  if (threadIdx.x == 0) {
    float aux = 0.f; int off = 0;
    for (int e = 0; e < EE; ++e) {
      aux += ((float)counts[e] / (float)TT) * (P_sum[e] / (float)TT);
      offsets[e] = off; off += counts[e];
    }
    *out_aux = aux * (float)EE;
  }
}

// ---------------- G1: H = silu(Xg @ w1[e]) * (Xg @ w3[e]) -> Hbuf (bf16) ----------------
// grid: (HH/128, TT/128, EE); block 256 (4 waves, 2x2)
// B LDS layout: [n][k-unit] stride 40 shorts, 16B k-units XOR-swizzled by (n>>3)&3
__global__ __launch_bounds__(256, 2) void g1_kernel(
    const float* __restrict__ x, const float* __restrict__ w1, const float* __restrict__ w3,
    const int* __restrict__ counts, const int* __restrict__ offsets,
    const int* __restrict__ list_token, short* __restrict__ Hbuf)
{
  const int e = blockIdx.z, rb = blockIdx.y, nb = blockIdx.x;
  const int cnt = counts[e];
  if (rb * 128 >= cnt) return;
  __shared__ short Asm[128 * 40];
  __shared__ short B1sm[128 * 40];
  __shared__ short B3sm[128 * 40];
  const int tid = threadIdx.x, lane = tid & 63, wv = tid >> 6;
  const int wm = (wv >> 1) * 64, wn = (wv & 1) * 64;
  const int quad = lane >> 4, l16 = lane & 15;
  floatx4 acc1[4][4] = {{{0.f}}};
  floatx4 acc3[4][4] = {{{0.f}}};
  // A staging assignment (unchanged: ~conflict-free)
  const int ar = tid >> 3, ak = (tid & 7) * 4;
  // B staging assignment: thread owns cols {2bp, 2bp+1}, k-octet bq (8 contiguous k)
  const int bp = tid & 63;         // column pair
  const int bq = tid >> 6;         // k-octet 0..3
  const int bswz = (bq ^ ((bp >> 2) & 3)) * 8;    // swizzled 16B unit (short offset)
  const int bo0 = (2 * bp) * 40 + bswz;
  const int bo1 = bo0 + 40;
  // hoisted LDS read offsets (short index)
  int aro[4], bro[4];
#pragma unroll
  for (int mi = 0; mi < 4; ++mi) aro[mi] = (wm + mi * 16 + l16) * 40 + quad * 8;
#pragma unroll
  for (int ni = 0; ni < 4; ++ni) {
    int nl = wn + ni * 16 + l16;
    bro[ni] = nl * 40 + ((quad ^ ((nl >> 3) & 3)) * 8);
  }
  int tok[4];
#pragma unroll
  for (int i = 0; i < 4; ++i) {
    int gr = rb * 128 + ar + 32 * i;
    tok[i] = (gr < cnt) ? list_token[e * TT + gr] : list_token[e * TT];
  }
  const float* w1e = w1 + (size_t)e * DD * HH + (size_t)nb * 128;
  const float* w3e = w3 + (size_t)e * DD * HH + (size_t)nb * 128;

  for (int k0 = 0; k0 < DD; k0 += 32) {
    __syncthreads();
    // A tile [128 x 32] fp32->bf16, row-major stride 40 (k contiguous)
#pragma unroll
    for (int i = 0; i < 4; ++i) {
      int r = ar + 32 * i;
      float4 v = *(const float4*)(x + (size_t)tok[i] * DD + k0 + ak);
      short4 sv = make_short4(f2bf(v.x), f2bf(v.y), f2bf(v.z), f2bf(v.w));
      *(short4*)&Asm[r * 40 + ak] = sv;
    }
    // B tiles: coalesced float2 column-pair loads, 16B k-contiguous swizzled writes
    {
      float2 u[8];
#pragma unroll
      for (int j = 0; j < 8; ++j)
        u[j] = *(const float2*)(w1e + (size_t)(k0 + bq * 8 + j) * HH + 2 * bp);
      shortx8 p0, p1;
#pragma unroll
      for (int j = 0; j < 8; ++j) { p0[j] = f2bf(u[j].x); p1[j] = f2bf(u[j].y); }
      *(shortx8*)&B1sm[bo0] = p0;
      *(shortx8*)&B1sm[bo1] = p1;
    }
    {
      float2 u[8];
#pragma unroll
      for (int j = 0; j < 8; ++j)
        u[j] = *(const float2*)(w3e + (size_t)(k0 + bq * 8 + j) * HH + 2 * bp);
      shortx8 p0, p1;
#pragma unroll
      for (int j = 0; j < 8; ++j) { p0[j] = f2bf(u[j].x); p1[j] = f2bf(u[j].y); }
      *(shortx8*)&B3sm[bo0] = p0;
      *(shortx8*)&B3sm[bo1] = p1;
    }
    __syncthreads();
    bf16x8 af[4], b1f[4], b3f[4];
#pragma unroll
    for (int mi = 0; mi < 4; ++mi) af[mi] = *(const bf16x8*)&Asm[aro[mi]];
#pragma unroll
    for (int ni = 0; ni < 4; ++ni) {
      b1f[ni] = *(const bf16x8*)&B1sm[bro[ni]];
      b3f[ni] = *(const bf16x8*)&B3sm[bro[ni]];
    }
#pragma unroll
    for (int mi = 0; mi < 4; ++mi)
#pragma unroll
      for (int ni = 0; ni < 4; ++ni) {
        acc1[mi][ni] = __builtin_amdgcn_mfma_f32_16x16x32_bf16(af[mi], b1f[ni], acc1[mi][ni], 0, 0, 0);
        acc3[mi][ni] = __builtin_amdgcn_mfma_f32_16x16x32_bf16(af[mi], b3f[ni], acc3[mi][ni], 0, 0, 0);
      }
  }
  // epilogue: SwiGLU, store bf16 H rows
  const int off = offsets[e];
#pragma unroll
  for (int mi = 0; mi < 4; ++mi)
#pragma unroll
    for (int r = 0; r < 4; ++r) {
      int row = wm + mi * 16 + quad * 4 + r;
      int grow = rb * 128 + row;
      if (grow < cnt) {
        size_t rowbase = (size_t)(off + grow) * HH + (size_t)nb * 128 + wn;
#pragma unroll
        for (int ni = 0; ni < 4; ++ni) {
          float a = acc1[mi][ni][r], b = acc3[mi][ni][r];
          float h = a / (1.f + __expf(-a)) * b;   // silu(a) * b
          Hbuf[rowbase + ni * 16 + l16] = f2bf(h);
        }
      }
    }
}

// ---------------- G2: out[token] += coef * (Hrows @ w2[e]) ----------------
// grid: (DD/128, TT/128, EE); block 256
__global__ __launch_bounds__(256, 2) void g2_kernel(
    const short* __restrict__ Hbuf, const float* __restrict__ w2,
    const int* __restrict__ counts, const int* __restrict__ offsets,
    const int* __restrict__ list_token, const float* __restrict__ list_coef,
    float* __restrict__ out)
{
  const int e = blockIdx.z, rb = blockIdx.y, nb = blockIdx.x;
  const int cnt = counts[e];
  if (rb * 128 >= cnt) return;
  __shared__ short Asm[128 * 40];
  __shared__ short Bsm[128 * 40];
  const int tid = threadIdx.x, lane = tid & 63, wv = tid >> 6;
  const int wm = (wv >> 1) * 64, wn = (wv & 1) * 64;
  const int quad = lane >> 4, l16 = lane & 15;
  floatx4 acc[4][4] = {{{0.f}}};
  const int ar = tid >> 3, ak = (tid & 7) * 4;
  const int bp = tid & 63;
  const int bq = tid >> 6;
  const int bswz = (bq ^ ((bp >> 2) & 3)) * 8;
  const int bo0 = (2 * bp) * 40 + bswz;
  const int bo1 = bo0 + 40;
  int aro[4], bro[4];
#pragma unroll
  for (int mi = 0; mi < 4; ++mi) aro[mi] = (wm + mi * 16 + l16) * 40 + quad * 8;
#pragma unroll
  for (int ni = 0; ni < 4; ++ni) {
    int nl = wn + ni * 16 + l16;
    bro[ni] = nl * 40 + ((quad ^ ((nl >> 3) & 3)) * 8);
  }
  const int off = offsets[e];
  size_t hrow[4];
#pragma unroll
  for (int i = 0; i < 4; ++i) {
    int gr = rb * 128 + ar + 32 * i;
    int cg = (gr < cnt) ? gr : (cnt - 1);
    hrow[i] = (size_t)(off + cg) * HH;
  }
  const float* w2e = w2 + (size_t)e * HH * DD + (size_t)nb * 128;

  for (int k0 = 0; k0 < HH; k0 += 32) {
    __syncthreads();
#pragma unroll
    for (int i = 0; i < 4; ++i) {
      int r = ar + 32 * i;
      short4 sv = *(const short4*)(Hbuf + hrow[i] + k0 + ak);
      *(short4*)&Asm[r * 40 + ak] = sv;
    }
    {
      float2 u[8];
#pragma unroll
      for (int j = 0; j < 8; ++j)
        u[j] = *(const float2*)(w2e + (size_t)(k0 + bq * 8 + j) * DD + 2 * bp);
      shortx8 p0, p1;
#pragma unroll
      for (int j = 0; j < 8; ++j) { p0[j] = f2bf(u[j].x); p1[j] = f2bf(u[j].y); }
      *(shortx8*)&Bsm[bo0] = p0;
      *(shortx8*)&Bsm[bo1] = p1;
    }
    __syncthreads();
    bf16x8 af[4], bf[4];
#pragma unroll
    for (int mi = 0; mi < 4; ++mi) af[mi] = *(const bf16x8*)&Asm[aro[mi]];
#pragma unroll
    for (int ni = 0; ni < 4; ++ni) bf[ni] = *(const bf16x8*)&Bsm[bro[ni]];
#pragma unroll
    for (int mi = 0; mi < 4; ++mi)
#pragma unroll
      for (int ni = 0; ni < 4; ++ni)
        acc[mi][ni] = __builtin_amdgcn_mfma_f32_16x16x32_bf16(af[mi], bf[ni], acc[mi][ni], 0, 0, 0);
  }
  // epilogue: weighted scatter-add into out rows
#pragma unroll
  for (int mi = 0; mi < 4; ++mi)
#pragma unroll
    for (int r = 0; r < 4; ++r) {
      int row = wm + mi * 16 + quad * 4 + r;
      int grow = rb * 128 + row;
      if (grow < cnt) {
        int tokid = list_token[e * TT + grow];
        float coef = list_coef[e * TT + grow];
        float* orow = out + (size_t)tokid * DD + (size_t)nb * 128 + wn;
#pragma unroll
        for (int ni = 0; ni < 4; ++ni)
          atomicAdd(&orow[ni * 16 + l16], coef * acc[mi][ni][r]);
      }
    }
}

extern "C" void kernel_launch(void* const* d_in, const int* in_sizes, int n_in,
                              void* d_out, int out_size, void* d_ws, size_t ws_size,
                              hipStream_t stream)
{
  const float* x  = (const float*)d_in[0];
  const float* rw = (const float*)d_in[1];
  const float* w1 = (const float*)d_in[2];
  const float* w3 = (const float*)d_in[3];
  const float* w2 = (const float*)d_in[4];
  float* out = (float*)d_out;

  char* ws = (char*)d_ws;
  int*   counts    = (int*)(ws + 0);                       // 8 ints
  float* P_sum     = (float*)(ws + 64);                    // 8 floats
  int*   offsets   = (int*)(ws + 128);                     // 8 ints
  int*   list_tok  = (int*)(ws + 1024);                    // E*T ints   (256 KB)
  float* list_coef = (float*)(ws + 1024 + EE * TT * 4);    // E*T floats (256 KB)
  short* Hbuf      = (short*)(ws + (1 << 20));             // 16384 x 2048 bf16 (64 MB)

  hipMemsetAsync(ws, 0, 128, stream);                                   // counts + P_sum
  hipMemsetAsync(d_out, 0, (size_t)TT * DD * sizeof(float), stream);    // scatter target

  router_kernel<<<512, 256, 0, stream>>>(x, rw, counts, P_sum, list_tok, list_coef);
  aux_kernel<<<1, 64, 0, stream>>>(counts, P_sum, offsets, out + (size_t)TT * DD);
  g1_kernel<<<dim3(HH / 128, TT / 128, EE), 256, 0, stream>>>(x, w1, w3, counts, offsets, list_tok, Hbuf);
  g2_kernel<<<dim3(DD / 128, TT / 128, EE), 256, 0, stream>>>(Hbuf, w2, counts, offsets, list_tok, list_coef, out);
}

// Round 3
// 759.813 us; speedup vs baseline: 1.8502x; 1.1701x over previous
//
#include <hip/hip_runtime.h>
#include <hip/hip_bf16.h>

// Problem constants (B=2, S=4096 -> T=8192 tokens)
#define TT 8192
#define DD 1024
#define HH 2048
#define EE 8

typedef __bf16 bf16x8 __attribute__((ext_vector_type(8)));
typedef float floatx4 __attribute__((ext_vector_type(4)));
typedef short shortx8 __attribute__((ext_vector_type(8)));

// float -> bf16 bits, round-to-nearest-even
__device__ __forceinline__ short f2bf(float f) {
  unsigned u = __float_as_uint(f);
  u += 0x7fffu + ((u >> 16) & 1u);
  return (short)(u >> 16);
}

// async global->LDS, 16B per lane; LDS dest = wave-uniform base + lane*16
__device__ __forceinline__ void gld16(const void* g, void* l) {
  __builtin_amdgcn_global_load_lds((const __attribute__((address_space(1))) void*)g,
                                   (__attribute__((address_space(3))) void*)l, 16, 0, 0);
}

// ---------------- Router: logits, top-2, softmax, expert lists ----------------
__global__ __launch_bounds__(256) void router_kernel(
    const float* __restrict__ x, const float* __restrict__ rw,
    int* __restrict__ counts, float* __restrict__ P_sum,
    int* __restrict__ list_token, float* __restrict__ list_coef)
{
  __shared__ float P_loc[EE];
  const int tid = threadIdx.x;
  if (tid < EE) P_loc[tid] = 0.f;
  __syncthreads();
  const int lane = tid & 63;
  const int wid = blockIdx.x * 4 + (tid >> 6);
  for (int ti = 0; ti < 4; ++ti) {
    const int t = wid * 4 + ti;
    float s[EE];
#pragma unroll
    for (int e = 0; e < EE; ++e) s[e] = 0.f;
    const float4* xp = (const float4*)(x + (size_t)t * DD);
#pragma unroll
    for (int j = 0; j < 4; ++j) {
      float4 xv = xp[j * 64 + lane];
#pragma unroll
      for (int e = 0; e < EE; ++e) {
        const float4* rp = (const float4*)(rw + e * DD);
        float4 rv = rp[j * 64 + lane];
        s[e] += xv.x * rv.x + xv.y * rv.y + xv.z * rv.z + xv.w * rv.w;
      }
    }
#pragma unroll
    for (int off = 32; off > 0; off >>= 1)
#pragma unroll
      for (int e = 0; e < EE; ++e)
        s[e] += __shfl_down(s[e], off);
    if (lane == 0) {
      int i0 = 0; float l0 = s[0];
      for (int e = 1; e < EE; ++e) if (s[e] > l0) { l0 = s[e]; i0 = e; }
      int i1 = -1; float l1 = -3.4e38f;
      for (int e = 0; e < EE; ++e) if (e != i0 && s[e] > l1) { l1 = s[e]; i1 = e; }
      const float g0 = 1.f / (1.f + __expf(l1 - l0));
      const float g1 = 1.f - g0;
      float pr[EE]; float sum = 0.f;
      for (int e = 0; e < EE; ++e) { pr[e] = __expf(s[e] - l0); sum += pr[e]; }
      const float inv = 1.f / sum;
      for (int e = 0; e < EE; ++e) atomicAdd(&P_loc[e], pr[e] * inv);
      int p0 = atomicAdd(&counts[i0], 1);
      list_token[i0 * TT + p0] = t; list_coef[i0 * TT + p0] = g0;
      int p1 = atomicAdd(&counts[i1], 1);
      list_token[i1 * TT + p1] = t; list_coef[i1 * TT + p1] = g1;
    }
  }
  __syncthreads();
  if (tid < EE) atomicAdd(&P_sum[tid], P_loc[tid]);
}

// ---------------- Aux loss + prefix-sum offsets ----------------
__global__ void aux_kernel(const int* __restrict__ counts, const float* __restrict__ P_sum,
                           int* __restrict__ offsets, float* __restrict__ out_aux)
{
  if (threadIdx.x == 0) {
    float aux = 0.f; int off = 0;
    for (int e = 0; e < EE; ++e) {
      aux += ((float)counts[e] / (float)TT) * (P_sum[e] / (float)TT);
      offsets[e] = off; off += counts[e];
    }
    *out_aux = aux * (float)EE;
  }
}

// ---------------- convert x fp32 -> bf16 (flat) ----------------
__global__ __launch_bounds__(256) void convx_kernel(const float* __restrict__ x, short* __restrict__ xb)
{
  size_t i = ((size_t)blockIdx.x * 256 + threadIdx.x) * 8;
  float4 a = *(const float4*)(x + i);
  float4 b = *(const float4*)(x + i + 4);
  shortx8 s;
  s[0] = f2bf(a.x); s[1] = f2bf(a.y); s[2] = f2bf(a.z); s[3] = f2bf(a.w);
  s[4] = f2bf(b.x); s[5] = f2bf(b.y); s[6] = f2bf(b.z); s[7] = f2bf(b.w);
  *(shortx8*)(xb + i) = s;
}

// ---------------- convert+transpose weight: in [R][C] fp32 -> out [C][R] bf16 ----------------
// grid: (C/64, R/64, E)
__global__ __launch_bounds__(256) void convt_kernel(const float* __restrict__ in, short* __restrict__ out,
                                                    int R, int C)
{
  __shared__ short T[64 * 74];   // input layout [r][c], stride 74 (bank-spread)
  const int t = threadIdx.x;
  const size_t eoff = (size_t)blockIdx.z * R * C;
  in += eoff; out += eoff;
  const int c0 = blockIdx.x * 64, r0 = blockIdx.y * 64;
#pragma unroll
  for (int p = 0; p < 4; ++p) {
    int r = p * 16 + (t >> 4), c4 = (t & 15) * 4;
    float4 v = *(const float4*)(in + (size_t)(r0 + r) * C + c0 + c4);
    short4 s = make_short4(f2bf(v.x), f2bf(v.y), f2bf(v.z), f2bf(v.w));
    *(short4*)&T[r * 74 + c4] = s;
  }
  __syncthreads();
#pragma unroll
  for (int q = 0; q < 2; ++q) {
    int u = q * 256 + t;
    int oc = u >> 3, k8 = (u & 7) * 8;
    shortx8 s;
#pragma unroll
    for (int j = 0; j < 8; ++j) s[j] = T[(k8 + j) * 74 + oc];
    *(shortx8*)&out[(size_t)(c0 + oc) * R + r0 + k8] = s;
  }
}

// ---------------- FAST G1: H = silu(Xg @ w1) * (Xg @ w3), bf16 pre-converted ----------------
// w1t/w3t: [E][H][D] bf16 (n-major). LDS tiles packed [row][k], 32 shorts/row.
// grid: (HH/128, TT/128, EE); block 256 (4 waves, 2x2)
__global__ __launch_bounds__(256, 2) void g1f_kernel(
    const short* __restrict__ xb, const short* __restrict__ w1t, const short* __restrict__ w3t,
    const int* __restrict__ counts, const int* __restrict__ offsets,
    const int* __restrict__ list_token, short* __restrict__ Hbuf)
{
  const int e = blockIdx.z, rb = blockIdx.y, nb = blockIdx.x;
  const int cnt = counts[e];
  if (rb * 128 >= cnt) return;
  __shared__ short Asm[128 * 32];
  __shared__ short B1sm[128 * 32];
  __shared__ short B3sm[128 * 32];
  const int tid = threadIdx.x, lane = tid & 63, wv = tid >> 6;
  const int wm = (wv >> 1) * 64, wn = (wv & 1) * 64;
  const int quad = lane >> 4, l16 = lane & 15;
  floatx4 acc1[4][4] = {{{0.f}}};
  floatx4 acc3[4][4] = {{{0.f}}};
  // A staging: thread handles rows ra, ra+64; 16B seg sa
  const int ra = tid >> 2, sa = (tid & 3) * 8;
  int tokA[2];
  {
    int r0 = rb * 128 + ra, r1 = r0 + 64;
    tokA[0] = (r0 < cnt) ? list_token[e * TT + r0] : list_token[e * TT];
    tokA[1] = (r1 < cnt) ? list_token[e * TT + r1] : list_token[e * TT];
  }
  // B via global_load_lds: wave wv covers rows [wv*32, wv*32+32)
  const int brow = wv * 32 + (lane >> 2);
  const int bcb = (lane & 3) * 16;   // byte offset within 64-B row chunk
  const char* w1g = (const char*)(w1t + (size_t)e * HH * DD + (size_t)(nb * 128 + brow) * DD) + bcb;
  const char* w3g = (const char*)(w3t + (size_t)e * HH * DD + (size_t)(nb * 128 + brow) * DD) + bcb;
  char* b1l = (char*)B1sm + wv * 2048;
  char* b3l = (char*)B3sm + wv * 2048;
  int aro[4], bro[4];
#pragma unroll
  for (int mi = 0; mi < 4; ++mi) aro[mi] = (wm + mi * 16 + l16) * 32 + quad * 8;
#pragma unroll
  for (int ni = 0; ni < 4; ++ni) bro[ni] = (wn + ni * 16 + l16) * 32 + quad * 8;

  for (int k0 = 0; k0 < DD; k0 += 32) {
    __syncthreads();
    shortx8 va0 = *(const shortx8*)(xb + (size_t)tokA[0] * DD + k0 + sa);
    shortx8 va1 = *(const shortx8*)(xb + (size_t)tokA[1] * DD + k0 + sa);
    gld16(w1g + (size_t)k0 * 2, b1l);
    gld16(w1g + (size_t)k0 * 2 + 16 * DD * 2, b1l + 1024);
    gld16(w3g + (size_t)k0 * 2, b3l);
    gld16(w3g + (size_t)k0 * 2 + 16 * DD * 2, b3l + 1024);
    *(shortx8*)&Asm[ra * 32 + sa] = va0;
    *(shortx8*)&Asm[(ra + 64) * 32 + sa] = va1;
    __syncthreads();
    bf16x8 af[4], b1f[4], b3f[4];
#pragma unroll
    for (int mi = 0; mi < 4; ++mi) af[mi] = *(const bf16x8*)&Asm[aro[mi]];
#pragma unroll
    for (int ni = 0; ni < 4; ++ni) {
      b1f[ni] = *(const bf16x8*)&B1sm[bro[ni]];
      b3f[ni] = *(const bf16x8*)&B3sm[bro[ni]];
    }
#pragma unroll
    for (int mi = 0; mi < 4; ++mi)
#pragma unroll
      for (int ni = 0; ni < 4; ++ni) {
        acc1[mi][ni] = __builtin_amdgcn_mfma_f32_16x16x32_bf16(af[mi], b1f[ni], acc1[mi][ni], 0, 0, 0);
        acc3[mi][ni] = __builtin_amdgcn_mfma_f32_16x16x32_bf16(af[mi], b3f[ni], acc3[mi][ni], 0, 0, 0);
      }
  }
  const int off = offsets[e];
#pragma unroll
  for (int mi = 0; mi < 4; ++mi)
#pragma unroll
    for (int r = 0; r < 4; ++r) {
      int row = wm + mi * 16 + quad * 4 + r;
      int grow = rb * 128 + row;
      if (grow < cnt) {
        size_t rowbase = (size_t)(off + grow) * HH + (size_t)nb * 128 + wn;
#pragma unroll
        for (int ni = 0; ni < 4; ++ni) {
          float a = acc1[mi][ni][r], b = acc3[mi][ni][r];
          float h = a / (1.f + __expf(-a)) * b;
          Hbuf[rowbase + ni * 16 + l16] = f2bf(h);
        }
      }
    }
}

// ---------------- FAST G2: out[token] += coef * (Hrows @ w2) ----------------
// w2t: [E][D][H] bf16. A (Hbuf rows) is slot-contiguous -> both tiles via global_load_lds.
// grid: (DD/128, TT/128, EE); block 256
__global__ __launch_bounds__(256, 2) void g2f_kernel(
    const short* __restrict__ Hbuf, const short* __restrict__ w2t,
    const int* __restrict__ counts, const int* __restrict__ offsets,
    const int* __restrict__ list_token, const float* __restrict__ list_coef,
    float* __restrict__ out)
{
  const int e = blockIdx.z, rb = blockIdx.y, nb = blockIdx.x;
  const int cnt = counts[e];
  if (rb * 128 >= cnt) return;
  __shared__ short Asm[128 * 32];
  __shared__ short Bsm[128 * 32];
  const int tid = threadIdx.x, lane = tid & 63, wv = tid >> 6;
  const int wm = (wv >> 1) * 64, wn = (wv & 1) * 64;
  const int quad = lane >> 4, l16 = lane & 15;
  floatx4 acc[4][4] = {{{0.f}}};
  const int off = offsets[e];
  const int qrow = wv * 32 + (lane >> 2);
  const int qcb = (lane & 3) * 16;
  const char* ag = (const char*)(Hbuf + (size_t)(off + rb * 128 + qrow) * HH) + qcb;
  const char* bg = (const char*)(w2t + (size_t)e * DD * HH + (size_t)(nb * 128 + qrow) * HH) + qcb;
  char* al = (char*)Asm + wv * 2048;
  char* bl = (char*)Bsm + wv * 2048;
  int aro[4], bro[4];
#pragma unroll
  for (int mi = 0; mi < 4; ++mi) aro[mi] = (wm + mi * 16 + l16) * 32 + quad * 8;
#pragma unroll
  for (int ni = 0; ni < 4; ++ni) bro[ni] = (wn + ni * 16 + l16) * 32 + quad * 8;

  for (int k0 = 0; k0 < HH; k0 += 32) {
    __syncthreads();
    gld16(ag + (size_t)k0 * 2, al);
    gld16(ag + (size_t)k0 * 2 + 16 * HH * 2, al + 1024);
    gld16(bg + (size_t)k0 * 2, bl);
    gld16(bg + (size_t)k0 * 2 + 16 * HH * 2, bl + 1024);
    __syncthreads();
    bf16x8 af[4], bf[4];
#pragma unroll
    for (int mi = 0; mi < 4; ++mi) af[mi] = *(const bf16x8*)&Asm[aro[mi]];
#pragma unroll
    for (int ni = 0; ni < 4; ++ni) bf[ni] = *(const bf16x8*)&Bsm[bro[ni]];
#pragma unroll
    for (int mi = 0; mi < 4; ++mi)
#pragma unroll
      for (int ni = 0; ni < 4; ++ni)
        acc[mi][ni] = __builtin_amdgcn_mfma_f32_16x16x32_bf16(af[mi], bf[ni], acc[mi][ni], 0, 0, 0);
  }
#pragma unroll
  for (int mi = 0; mi < 4; ++mi)
#pragma unroll
    for (int r = 0; r < 4; ++r) {
      int row = wm + mi * 16 + quad * 4 + r;
      int grow = rb * 128 + row;
      if (grow < cnt) {
        int tokid = list_token[e * TT + grow];
        float coef = list_coef[e * TT + grow];
        float* orow = out + (size_t)tokid * DD + (size_t)nb * 128 + wn;
#pragma unroll
        for (int ni = 0; ni < 4; ++ni)
          atomicAdd(&orow[ni * 16 + l16], coef * acc[mi][ni][r]);
      }
    }
}

// ================= FALLBACK (round-2 proven path, used if ws too small) =================
__global__ __launch_bounds__(256, 2) void g1s_kernel(
    const float* __restrict__ x, const float* __restrict__ w1, const float* __restrict__ w3,
    const int* __restrict__ counts, const int* __restrict__ offsets,
    const int* __restrict__ list_token, short* __restrict__ Hbuf)
{
  const int e = blockIdx.z, rb = blockIdx.y, nb = blockIdx.x;
  const int cnt = counts[e];
  if (rb * 128 >= cnt) return;
  __shared__ short Asm[128 * 40];
  __shared__ short B1sm[128 * 40];
  __shared__ short B3sm[128 * 40];
  const int tid = threadIdx.x, lane = tid & 63, wv = tid >> 6;
  const int wm = (wv >> 1) * 64, wn = (wv & 1) * 64;
  const int quad = lane >> 4, l16 = lane & 15;
  floatx4 acc1[4][4] = {{{0.f}}};
  floatx4 acc3[4][4] = {{{0.f}}};
  const int ar = tid >> 3, ak = (tid & 7) * 4;
  const int bp = tid & 63, bq = tid >> 6;
  const int bswz = (bq ^ ((bp >> 2) & 3)) * 8;
  const int bo0 = (2 * bp) * 40 + bswz, bo1 = bo0 + 40;
  int aro[4], bro[4];
#pragma unroll
  for (int mi = 0; mi < 4; ++mi) aro[mi] = (wm + mi * 16 + l16) * 40 + quad * 8;
#pragma unroll
  for (int ni = 0; ni < 4; ++ni) {
    int nl = wn + ni * 16 + l16;
    bro[ni] = nl * 40 + ((quad ^ ((nl >> 3) & 3)) * 8);
  }
  int tok[4];
#pragma unroll
  for (int i = 0; i < 4; ++i) {
    int gr = rb * 128 + ar + 32 * i;
    tok[i] = (gr < cnt) ? list_token[e * TT + gr] : list_token[e * TT];
  }
  const float* w1e = w1 + (size_t)e * DD * HH + (size_t)nb * 128;
  const float* w3e = w3 + (size_t)e * DD * HH + (size_t)nb * 128;
  for (int k0 = 0; k0 < DD; k0 += 32) {
    __syncthreads();
#pragma unroll
    for (int i = 0; i < 4; ++i) {
      int r = ar + 32 * i;
      float4 v = *(const float4*)(x + (size_t)tok[i] * DD + k0 + ak);
      short4 sv = make_short4(f2bf(v.x), f2bf(v.y), f2bf(v.z), f2bf(v.w));
      *(short4*)&Asm[r * 40 + ak] = sv;
    }
    {
      float2 u[8];
#pragma unroll
      for (int j = 0; j < 8; ++j) u[j] = *(const float2*)(w1e + (size_t)(k0 + bq * 8 + j) * HH + 2 * bp);
      shortx8 p0, p1;
#pragma unroll
      for (int j = 0; j < 8; ++j) { p0[j] = f2bf(u[j].x); p1[j] = f2bf(u[j].y); }
      *(shortx8*)&B1sm[bo0] = p0; *(shortx8*)&B1sm[bo1] = p1;
    }
    {
      float2 u[8];
#pragma unroll
      for (int j = 0; j < 8; ++j) u[j] = *(const float2*)(w3e + (size_t)(k0 + bq * 8 + j) * HH + 2 * bp);
      shortx8 p0, p1;
#pragma unroll
      for (int j = 0; j < 8; ++j) { p0[j] = f2bf(u[j].x); p1[j] = f2bf(u[j].y); }
      *(shortx8*)&B3sm[bo0] = p0; *(shortx8*)&B3sm[bo1] = p1;
    }
    __syncthreads();
    bf16x8 af[4], b1f[4], b3f[4];
#pragma unroll
    for (int mi = 0; mi < 4; ++mi) af[mi] = *(const bf16x8*)&Asm[aro[mi]];
#pragma unroll
    for (int ni = 0; ni < 4; ++ni) {
      b1f[ni] = *(const bf16x8*)&B1sm[bro[ni]];
      b3f[ni] = *(const bf16x8*)&B3sm[bro[ni]];
    }
#pragma unroll
    for (int mi = 0; mi < 4; ++mi)
#pragma unroll
      for (int ni = 0; ni < 4; ++ni) {
        acc1[mi][ni] = __builtin_amdgcn_mfma_f32_16x16x32_bf16(af[mi], b1f[ni], acc1[mi][ni], 0, 0, 0);
        acc3[mi][ni] = __builtin_amdgcn_mfma_f32_16x16x32_bf16(af[mi], b3f[ni], acc3[mi][ni], 0, 0, 0);
      }
  }
  const int off = offsets[e];
#pragma unroll
  for (int mi = 0; mi < 4; ++mi)
#pragma unroll
    for (int r = 0; r < 4; ++r) {
      int row = wm + mi * 16 + quad * 4 + r;
      int grow = rb * 128 + row;
      if (grow < cnt) {
        size_t rowbase = (size_t)(off + grow) * HH + (size_t)nb * 128 + wn;
#pragma unroll
        for (int ni = 0; ni < 4; ++ni) {
          float a = acc1[mi][ni][r], b = acc3[mi][ni][r];
          float h = a / (1.f + __expf(-a)) * b;
          Hbuf[rowbase + ni * 16 + l16] = f2bf(h);
        }
      }
    }
}

__global__ __launch_bounds__(256, 2) void g2s_kernel(
    const short* __restrict__ Hbuf, const float* __restrict__ w2,
    const int* __restrict__ counts, const int* __restrict__ offsets,
    const int* __restrict__ list_token, const float* __restrict__ list_coef,
    float* __restrict__ out)
{
  const int e = blockIdx.z, rb = blockIdx.y, nb = blockIdx.x;
  const int cnt = counts[e];
  if (rb * 128 >= cnt) return;
  __shared__ short Asm[128 * 40];
  __shared__ short Bsm[128 * 40];
  const int tid = threadIdx.x, lane = tid & 63, wv = tid >> 6;
  const int wm = (wv >> 1) * 64, wn = (wv & 1) * 64;
  const int quad = lane >> 4, l16 = lane & 15;
  floatx4 acc[4][4] = {{{0.f}}};
  const int ar = tid >> 3, ak = (tid & 7) * 4;
  const int bp = tid & 63, bq = tid >> 6;
  const int bswz = (bq ^ ((bp >> 2) & 3)) * 8;
  const int bo0 = (2 * bp) * 40 + bswz, bo1 = bo0 + 40;
  int aro[4], bro[4];
#pragma unroll
  for (int mi = 0; mi < 4; ++mi) aro[mi] = (wm + mi * 16 + l16) * 40 + quad * 8;
#pragma unroll
  for (int ni = 0; ni < 4; ++ni) {
    int nl = wn + ni * 16 + l16;
    bro[ni] = nl * 40 + ((quad ^ ((nl >> 3) & 3)) * 8);
  }
  const int off = offsets[e];
  size_t hrow[4];
#pragma unroll
  for (int i = 0; i < 4; ++i) {
    int gr = rb * 128 + ar + 32 * i;
    int cg = (gr < cnt) ? gr : (cnt - 1);
    hrow[i] = (size_t)(off + cg) * HH;
  }
  const float* w2e = w2 + (size_t)e * HH * DD + (size_t)nb * 128;
  for (int k0 = 0; k0 < HH; k0 += 32) {
    __syncthreads();
#pragma unroll
    for (int i = 0; i < 4; ++i) {
      int r = ar + 32 * i;
      short4 sv = *(const short4*)(Hbuf + hrow[i] + k0 + ak);
      *(short4*)&Asm[r * 40 + ak] = sv;
    }
    {
      float2 u[8];
#pragma unroll
      for (int j = 0; j < 8; ++j) u[j] = *(const float2*)(w2e + (size_t)(k0 + bq * 8 + j) * DD + 2 * bp);
      shortx8 p0, p1;
#pragma unroll
      for (int j = 0; j < 8; ++j) { p0[j] = f2bf(u[j].x); p1[j] = f2bf(u[j].y); }
      *(shortx8*)&Bsm[bo0] = p0; *(shortx8*)&Bsm[bo1] = p1;
    }
    __syncthreads();
    bf16x8 af[4], bf[4];
#pragma unroll
    for (int mi = 0; mi < 4; ++mi) af[mi] = *(const bf16x8*)&Asm[aro[mi]];
#pragma unroll
    for (int ni = 0; ni < 4; ++ni) bf[ni] = *(const bf16x8*)&Bsm[bro[ni]];
#pragma unroll
    for (int mi = 0; mi < 4; ++mi)
#pragma unroll
      for (int ni = 0; ni < 4; ++ni)
        acc[mi][ni] = __builtin_amdgcn_mfma_f32_16x16x32_bf16(af[mi], bf[ni], acc[mi][ni], 0, 0, 0);
  }
#pragma unroll
  for (int mi = 0; mi < 4; ++mi)
#pragma unroll
    for (int r = 0; r < 4; ++r) {
      int row = wm + mi * 16 + quad * 4 + r;
      int grow = rb * 128 + row;
      if (grow < cnt) {
        int tokid = list_token[e * TT + grow];
        float coef = list_coef[e * TT + grow];
        float* orow = out + (size_t)tokid * DD + (size_t)nb * 128 + wn;
#pragma unroll
        for (int ni = 0; ni < 4; ++ni)
          atomicAdd(&orow[ni * 16 + l16], coef * acc[mi][ni][r]);
      }
    }
}

extern "C" void kernel_launch(void* const* d_in, const int* in_sizes, int n_in,
                              void* d_out, int out_size, void* d_ws, size_t ws_size,
                              hipStream_t stream)
{
  const float* x  = (const float*)d_in[0];
  const float* rw = (const float*)d_in[1];
  const float* w1 = (const float*)d_in[2];
  const float* w3 = (const float*)d_in[3];
  const float* w2 = (const float*)d_in[4];
  float* out = (float*)d_out;

  char* ws = (char*)d_ws;
  int*   counts    = (int*)(ws + 0);
  float* P_sum     = (float*)(ws + 64);
  int*   offsets   = (int*)(ws + 128);
  int*   list_tok  = (int*)(ws + 1024);
  float* list_coef = (float*)(ws + 1024 + EE * TT * 4);

  // fast-path layout (bytes): hdr 1MB | W1T 32MB (reused as W2T) | W3T 32MB | XBF 16MB | HBUF 67.6MB
  const size_t OFF_W1T = 1u << 20;
  const size_t OFF_W3T = OFF_W1T + ((size_t)EE * DD * HH * 2);
  const size_t OFF_XBF = OFF_W3T + ((size_t)EE * DD * HH * 2);
  const size_t OFF_HB  = OFF_XBF + ((size_t)TT * DD * 2);
  const size_t NEED    = OFF_HB + ((size_t)(2 * TT + 128) * HH * 2);   // ~145.5 MiB

  hipMemsetAsync(ws, 0, 128, stream);
  hipMemsetAsync(d_out, 0, (size_t)TT * DD * sizeof(float), stream);

  router_kernel<<<512, 256, 0, stream>>>(x, rw, counts, P_sum, list_tok, list_coef);
  aux_kernel<<<1, 64, 0, stream>>>(counts, P_sum, offsets, out + (size_t)TT * DD);

  if (ws_size >= NEED) {
    short* W1T = (short*)(ws + OFF_W1T);
    short* W3T = (short*)(ws + OFF_W3T);
    short* XBF = (short*)(ws + OFF_XBF);
    short* HB  = (short*)(ws + OFF_HB);
    convx_kernel<<<TT * DD / 2048, 256, 0, stream>>>(x, XBF);
    convt_kernel<<<dim3(HH / 64, DD / 64, EE), 256, 0, stream>>>(w1, W1T, DD, HH);
    convt_kernel<<<dim3(HH / 64, DD / 64, EE), 256, 0, stream>>>(w3, W3T, DD, HH);
    g1f_kernel<<<dim3(HH / 128, TT / 128, EE), 256, 0, stream>>>(XBF, W1T, W3T, counts, offsets, list_tok, HB);
    // w2t overwrites W1T region after g1 has consumed it (in-order stream)
    convt_kernel<<<dim3(DD / 64, HH / 64, EE), 256, 0, stream>>>(w2, W1T, HH, DD);
    g2f_kernel<<<dim3(DD / 128, TT / 128, EE), 256, 0, stream>>>(HB, W1T, counts, offsets, list_tok, list_coef, out);
  } else {
    short* HB = (short*)(ws + (1 << 20));
    g1s_kernel<<<dim3(HH / 128, TT / 128, EE), 256, 0, stream>>>(x, w1, w3, counts, offsets, list_tok, HB);
    g2s_kernel<<<dim3(DD / 128, TT / 128, EE), 256, 0, stream>>>(HB, w2, counts, offsets, list_tok, list_coef, out);
  }
}

// Round 4
// 593.335 us; speedup vs baseline: 2.3693x; 1.2806x over previous
//
#include <hip/hip_runtime.h>
#include <hip/hip_bf16.h>

// Problem constants (B=2, S=4096 -> T=8192 tokens)
#define TT 8192
#define DD 1024
#define HH 2048
#define EE 8

typedef __bf16 bf16x8 __attribute__((ext_vector_type(8)));
typedef float floatx4 __attribute__((ext_vector_type(4)));
typedef short shortx8 __attribute__((ext_vector_type(8)));

// float -> bf16 bits, round-to-nearest-even
__device__ __forceinline__ short f2bf(float f) {
  unsigned u = __float_as_uint(f);
  u += 0x7fffu + ((u >> 16) & 1u);
  return (short)(u >> 16);
}

// async global->LDS, 16B per lane; LDS dest = wave-uniform base + lane*16
__device__ __forceinline__ void gld16(const void* g, void* l) {
  __builtin_amdgcn_global_load_lds((const __attribute__((address_space(1))) void*)g,
                                   (__attribute__((address_space(3))) void*)l, 16, 0, 0);
}

// ---------------- Router: logits, top-2, softmax, expert lists, fused x->bf16 ----------------
// Grid 256 x 256 threads. Block handles 32 tokens (4 waves x 8). Global atomics are
// block-aggregated (8+8 per block) onto 64-B-padded counters (one line per expert) to
// kill the same-line fabric-atomic serialization that cost 197 us in round 3.
__global__ __launch_bounds__(256) void router_kernel(
    const float* __restrict__ x, const float* __restrict__ rw,
    int* __restrict__ cpad, float* __restrict__ ppad,
    int* __restrict__ list_token, float* __restrict__ list_coef,
    short* __restrict__ xb)
{
  __shared__ int   sE0[32], sE1[32], lcnt[EE], sbase[EE], lp0[32], lp1[32];
  __shared__ float sG0[32], sG1[32], sP[EE];
  const int tid = threadIdx.x;
  if (tid < EE) { sP[tid] = 0.f; lcnt[tid] = 0; }
  __syncthreads();
  const int lane = tid & 63, wv = tid >> 6;
  const int t0 = blockIdx.x * 32;
  for (int ti = 0; ti < 8; ++ti) {
    const int s = wv * 8 + ti;
    const int t = t0 + s;
    float sc[EE];
#pragma unroll
    for (int e = 0; e < EE; ++e) sc[e] = 0.f;
#pragma unroll
    for (int j = 0; j < 4; ++j) {
      float4 xv = *(const float4*)(x + (size_t)t * DD + j * 256 + lane * 4);
#pragma unroll
      for (int e = 0; e < EE; ++e) {
        float4 rv = *(const float4*)(rw + e * DD + j * 256 + lane * 4);
        sc[e] += xv.x * rv.x + xv.y * rv.y + xv.z * rv.z + xv.w * rv.w;
      }
      if (xb) {  // fused fp32 -> bf16 conversion of x (saves the convx pass)
        short4 sv = make_short4(f2bf(xv.x), f2bf(xv.y), f2bf(xv.z), f2bf(xv.w));
        *(short4*)(xb + (size_t)t * DD + j * 256 + lane * 4) = sv;
      }
    }
#pragma unroll
    for (int off = 32; off > 0; off >>= 1)
#pragma unroll
      for (int e = 0; e < EE; ++e)
        sc[e] += __shfl_down(sc[e], off);
    if (lane == 0) {
      int i0 = 0; float l0 = sc[0];
      for (int e = 1; e < EE; ++e) if (sc[e] > l0) { l0 = sc[e]; i0 = e; }
      int i1 = -1; float l1 = -3.4e38f;
      for (int e = 0; e < EE; ++e) if (e != i0 && sc[e] > l1) { l1 = sc[e]; i1 = e; }
      const float g0 = 1.f / (1.f + __expf(l1 - l0));
      float pr[EE]; float sum = 0.f;
      for (int e = 0; e < EE; ++e) { pr[e] = __expf(sc[e] - l0); sum += pr[e]; }
      const float inv = 1.f / sum;
      for (int e = 0; e < EE; ++e) atomicAdd(&sP[e], pr[e] * inv);
      sE0[s] = i0; sE1[s] = i1; sG0[s] = g0; sG1[s] = 1.f - g0;
    }
  }
  __syncthreads();
  if (tid < 32) {                       // local slot assignment
    lp0[tid] = atomicAdd(&lcnt[sE0[tid]], 1);
    lp1[tid] = atomicAdd(&lcnt[sE1[tid]], 1);
  }
  __syncthreads();
  if (tid < EE) {                       // one padded global atomic per expert
    sbase[tid] = atomicAdd(&cpad[tid * 16], lcnt[tid]);
    atomicAdd(&ppad[tid * 16], sP[tid]);
  }
  __syncthreads();
  if (tid < 32) {
    int e0 = sE0[tid], e1 = sE1[tid], t = t0 + tid;
    int p0 = sbase[e0] + lp0[tid];
    int p1 = sbase[e1] + lp1[tid];
    list_token[e0 * TT + p0] = t; list_coef[e0 * TT + p0] = sG0[tid];
    list_token[e1 * TT + p1] = t; list_coef[e1 * TT + p1] = sG1[tid];
  }
}

// ---------------- Aux loss + prefix-sum offsets ----------------
__global__ void aux_kernel(const int* __restrict__ cpad, const float* __restrict__ ppad,
                           int* __restrict__ offsets, float* __restrict__ out_aux)
{
  if (threadIdx.x == 0) {
    float aux = 0.f; int off = 0;
    for (int e = 0; e < EE; ++e) {
      aux += ((float)cpad[e * 16] / (float)TT) * (ppad[e * 16] / (float)TT);
      offsets[e] = off; off += cpad[e * 16];
    }
    *out_aux = aux * (float)EE;
  }
}

// ---------------- convert+transpose weight: in [R][C] fp32 -> out [C][R] bf16 ----------------
// grid: (C/64, R/64, E)
__global__ __launch_bounds__(256) void convt_kernel(const float* __restrict__ in, short* __restrict__ out,
                                                    int R, int C)
{
  __shared__ short T[64 * 74];
  const int t = threadIdx.x;
  const size_t eoff = (size_t)blockIdx.z * R * C;
  in += eoff; out += eoff;
  const int c0 = blockIdx.x * 64, r0 = blockIdx.y * 64;
#pragma unroll
  for (int p = 0; p < 4; ++p) {
    int r = p * 16 + (t >> 4), c4 = (t & 15) * 4;
    float4 v = *(const float4*)(in + (size_t)(r0 + r) * C + c0 + c4);
    short4 s = make_short4(f2bf(v.x), f2bf(v.y), f2bf(v.z), f2bf(v.w));
    *(short4*)&T[r * 74 + c4] = s;
  }
  __syncthreads();
#pragma unroll
  for (int q = 0; q < 2; ++q) {
    int u = q * 256 + t;
    int oc = u >> 3, k8 = (u & 7) * 8;
    shortx8 s;
#pragma unroll
    for (int j = 0; j < 8; ++j) s[j] = T[(k8 + j) * 74 + oc];
    *(shortx8*)&out[(size_t)(c0 + oc) * R + r0 + k8] = s;
  }
}

// ---------------- FAST G1: H = silu(Xg @ w1) * (Xg @ w3); all staging via global_load_lds ----
// w1t/w3t: [E][H][D] bf16 (n-major). LDS tiles packed [row][k], 32 shorts/row.
// grid: (HH/128, TT/128, EE); block 256 (4 waves, 2x2)
__global__ __launch_bounds__(256, 2) void g1f_kernel(
    const short* __restrict__ xb, const short* __restrict__ w1t, const short* __restrict__ w3t,
    const int* __restrict__ cpad, const int* __restrict__ offsets,
    const int* __restrict__ list_token, short* __restrict__ Hbuf)
{
  const int e = blockIdx.z, rb = blockIdx.y, nb = blockIdx.x;
  const int cnt = cpad[e * 16];
  if (rb * 128 >= cnt) return;
  __shared__ short Asm[128 * 32];
  __shared__ short B1sm[128 * 32];
  __shared__ short B3sm[128 * 32];
  const int tid = threadIdx.x, lane = tid & 63, wv = tid >> 6;
  const int wm = (wv >> 1) * 64, wn = (wv & 1) * 64;
  const int quad = lane >> 4, l16 = lane & 15;
  floatx4 acc1[4][4] = {{{0.f}}};
  floatx4 acc3[4][4] = {{{0.f}}};
  // A via global_load_lds: wave wv covers rows [wv*32, wv*32+32); 4 lanes per row
  const int rlo = wv * 32 + (lane >> 2);
  int toklo, tokhi;
  {
    int glo = rb * 128 + rlo, ghi = glo + 16;
    toklo = (glo < cnt) ? list_token[e * TT + glo] : list_token[e * TT];
    tokhi = (ghi < cnt) ? list_token[e * TT + ghi] : list_token[e * TT];
  }
  const char* aglo = (const char*)(xb + (size_t)toklo * DD) + (lane & 3) * 16;
  const char* aghi = (const char*)(xb + (size_t)tokhi * DD) + (lane & 3) * 16;
  char* al = (char*)Asm + wv * 2048;
  // B via global_load_lds: wave wv covers rows [wv*32, wv*32+32)
  const int brow = wv * 32 + (lane >> 2);
  const int bcb = (lane & 3) * 16;
  const char* w1g = (const char*)(w1t + (size_t)e * HH * DD + (size_t)(nb * 128 + brow) * DD) + bcb;
  const char* w3g = (const char*)(w3t + (size_t)e * HH * DD + (size_t)(nb * 128 + brow) * DD) + bcb;
  char* b1l = (char*)B1sm + wv * 2048;
  char* b3l = (char*)B3sm + wv * 2048;
  int aro[4], bro[4];
#pragma unroll
  for (int mi = 0; mi < 4; ++mi) aro[mi] = (wm + mi * 16 + l16) * 32 + quad * 8;
#pragma unroll
  for (int ni = 0; ni < 4; ++ni) bro[ni] = (wn + ni * 16 + l16) * 32 + quad * 8;

  for (int k0 = 0; k0 < DD; k0 += 32) {
    __syncthreads();
    gld16(aglo + (size_t)k0 * 2, al);
    gld16(aghi + (size_t)k0 * 2, al + 1024);
    gld16(w1g + (size_t)k0 * 2, b1l);
    gld16(w1g + (size_t)k0 * 2 + 16 * DD * 2, b1l + 1024);
    gld16(w3g + (size_t)k0 * 2, b3l);
    gld16(w3g + (size_t)k0 * 2 + 16 * DD * 2, b3l + 1024);
    __syncthreads();
    bf16x8 af[4], b1f[4], b3f[4];
#pragma unroll
    for (int mi = 0; mi < 4; ++mi) af[mi] = *(const bf16x8*)&Asm[aro[mi]];
#pragma unroll
    for (int ni = 0; ni < 4; ++ni) {
      b1f[ni] = *(const bf16x8*)&B1sm[bro[ni]];
      b3f[ni] = *(const bf16x8*)&B3sm[bro[ni]];
    }
#pragma unroll
    for (int mi = 0; mi < 4; ++mi)
#pragma unroll
      for (int ni = 0; ni < 4; ++ni) {
        acc1[mi][ni] = __builtin_amdgcn_mfma_f32_16x16x32_bf16(af[mi], b1f[ni], acc1[mi][ni], 0, 0, 0);
        acc3[mi][ni] = __builtin_amdgcn_mfma_f32_16x16x32_bf16(af[mi], b3f[ni], acc3[mi][ni], 0, 0, 0);
      }
  }
  const int off = offsets[e];
#pragma unroll
  for (int mi = 0; mi < 4; ++mi)
#pragma unroll
    for (int r = 0; r < 4; ++r) {
      int row = wm + mi * 16 + quad * 4 + r;
      int grow = rb * 128 + row;
      if (grow < cnt) {
        size_t rowbase = (size_t)(off + grow) * HH + (size_t)nb * 128 + wn;
#pragma unroll
        for (int ni = 0; ni < 4; ++ni) {
          float a = acc1[mi][ni][r], b = acc3[mi][ni][r];
          float h = a / (1.f + __expf(-a)) * b;
          Hbuf[rowbase + ni * 16 + l16] = f2bf(h);
        }
      }
    }
}

// ---------------- FAST G2: out[token] += coef * (Hrows @ w2) ----------------
// w2t: [E][D][H] bf16. Both tiles via global_load_lds.
// grid: (DD/128, TT/128, EE); block 256
__global__ __launch_bounds__(256, 2) void g2f_kernel(
    const short* __restrict__ Hbuf, const short* __restrict__ w2t,
    const int* __restrict__ cpad, const int* __restrict__ offsets,
    const int* __restrict__ list_token, const float* __restrict__ list_coef,
    float* __restrict__ out)
{
  const int e = blockIdx.z, rb = blockIdx.y, nb = blockIdx.x;
  const int cnt = cpad[e * 16];
  if (rb * 128 >= cnt) return;
  __shared__ short Asm[128 * 32];
  __shared__ short Bsm[128 * 32];
  const int tid = threadIdx.x, lane = tid & 63, wv = tid >> 6;
  const int wm = (wv >> 1) * 64, wn = (wv & 1) * 64;
  const int quad = lane >> 4, l16 = lane & 15;
  floatx4 acc[4][4] = {{{0.f}}};
  const int off = offsets[e];
  const int qrow = wv * 32 + (lane >> 2);
  const int qcb = (lane & 3) * 16;
  const char* ag = (const char*)(Hbuf + (size_t)(off + rb * 128 + qrow) * HH) + qcb;
  const char* bg = (const char*)(w2t + (size_t)e * DD * HH + (size_t)(nb * 128 + qrow) * HH) + qcb;
  char* al = (char*)Asm + wv * 2048;
  char* bl = (char*)Bsm + wv * 2048;
  int aro[4], bro[4];
#pragma unroll
  for (int mi = 0; mi < 4; ++mi) aro[mi] = (wm + mi * 16 + l16) * 32 + quad * 8;
#pragma unroll
  for (int ni = 0; ni < 4; ++ni) bro[ni] = (wn + ni * 16 + l16) * 32 + quad * 8;

  for (int k0 = 0; k0 < HH; k0 += 32) {
    __syncthreads();
    gld16(ag + (size_t)k0 * 2, al);
    gld16(ag + (size_t)k0 * 2 + 16 * HH * 2, al + 1024);
    gld16(bg + (size_t)k0 * 2, bl);
    gld16(bg + (size_t)k0 * 2 + 16 * HH * 2, bl + 1024);
    __syncthreads();
    bf16x8 af[4], bf[4];
#pragma unroll
    for (int mi = 0; mi < 4; ++mi) af[mi] = *(const bf16x8*)&Asm[aro[mi]];
#pragma unroll
    for (int ni = 0; ni < 4; ++ni) bf[ni] = *(const bf16x8*)&Bsm[bro[ni]];
#pragma unroll
    for (int mi = 0; mi < 4; ++mi)
#pragma unroll
      for (int ni = 0; ni < 4; ++ni)
        acc[mi][ni] = __builtin_amdgcn_mfma_f32_16x16x32_bf16(af[mi], bf[ni], acc[mi][ni], 0, 0, 0);
  }
#pragma unroll
  for (int mi = 0; mi < 4; ++mi)
#pragma unroll
    for (int r = 0; r < 4; ++r) {
      int row = wm + mi * 16 + quad * 4 + r;
      int grow = rb * 128 + row;
      if (grow < cnt) {
        int tokid = list_token[e * TT + grow];
        float coef = list_coef[e * TT + grow];
        float* orow = out + (size_t)tokid * DD + (size_t)nb * 128 + wn;
#pragma unroll
        for (int ni = 0; ni < 4; ++ni)
          atomicAdd(&orow[ni * 16 + l16], coef * acc[mi][ni][r]);
      }
    }
}

// ================= FALLBACK (round-2 proven path, used if ws too small) =================
__global__ __launch_bounds__(256, 2) void g1s_kernel(
    const float* __restrict__ x, const float* __restrict__ w1, const float* __restrict__ w3,
    const int* __restrict__ cpad, const int* __restrict__ offsets,
    const int* __restrict__ list_token, short* __restrict__ Hbuf)
{
  const int e = blockIdx.z, rb = blockIdx.y, nb = blockIdx.x;
  const int cnt = cpad[e * 16];
  if (rb * 128 >= cnt) return;
  __shared__ short Asm[128 * 40];
  __shared__ short B1sm[128 * 40];
  __shared__ short B3sm[128 * 40];
  const int tid = threadIdx.x, lane = tid & 63, wv = tid >> 6;
  const int wm = (wv >> 1) * 64, wn = (wv & 1) * 64;
  const int quad = lane >> 4, l16 = lane & 15;
  floatx4 acc1[4][4] = {{{0.f}}};
  floatx4 acc3[4][4] = {{{0.f}}};
  const int ar = tid >> 3, ak = (tid & 7) * 4;
  const int bp = tid & 63, bq = tid >> 6;
  const int bswz = (bq ^ ((bp >> 2) & 3)) * 8;
  const int bo0 = (2 * bp) * 40 + bswz, bo1 = bo0 + 40;
  int aro[4], bro[4];
#pragma unroll
  for (int mi = 0; mi < 4; ++mi) aro[mi] = (wm + mi * 16 + l16) * 40 + quad * 8;
#pragma unroll
  for (int ni = 0; ni < 4; ++ni) {
    int nl = wn + ni * 16 + l16;
    bro[ni] = nl * 40 + ((quad ^ ((nl >> 3) & 3)) * 8);
  }
  int tok[4];
#pragma unroll
  for (int i = 0; i < 4; ++i) {
    int gr = rb * 128 + ar + 32 * i;
    tok[i] = (gr < cnt) ? list_token[e * TT + gr] : list_token[e * TT];
  }
  const float* w1e = w1 + (size_t)e * DD * HH + (size_t)nb * 128;
  const float* w3e = w3 + (size_t)e * DD * HH + (size_t)nb * 128;
  for (int k0 = 0; k0 < DD; k0 += 32) {
    __syncthreads();
#pragma unroll
    for (int i = 0; i < 4; ++i) {
      int r = ar + 32 * i;
      float4 v = *(const float4*)(x + (size_t)tok[i] * DD + k0 + ak);
      short4 sv = make_short4(f2bf(v.x), f2bf(v.y), f2bf(v.z), f2bf(v.w));
      *(short4*)&Asm[r * 40 + ak] = sv;
    }
    {
      float2 u[8];
#pragma unroll
      for (int j = 0; j < 8; ++j) u[j] = *(const float2*)(w1e + (size_t)(k0 + bq * 8 + j) * HH + 2 * bp);
      shortx8 p0, p1;
#pragma unroll
      for (int j = 0; j < 8; ++j) { p0[j] = f2bf(u[j].x); p1[j] = f2bf(u[j].y); }
      *(shortx8*)&B1sm[bo0] = p0; *(shortx8*)&B1sm[bo1] = p1;
    }
    {
      float2 u[8];
#pragma unroll
      for (int j = 0; j < 8; ++j) u[j] = *(const float2*)(w3e + (size_t)(k0 + bq * 8 + j) * HH + 2 * bp);
      shortx8 p0, p1;
#pragma unroll
      for (int j = 0; j < 8; ++j) { p0[j] = f2bf(u[j].x); p1[j] = f2bf(u[j].y); }
      *(shortx8*)&B3sm[bo0] = p0; *(shortx8*)&B3sm[bo1] = p1;
    }
    __syncthreads();
    bf16x8 af[4], b1f[4], b3f[4];
#pragma unroll
    for (int mi = 0; mi < 4; ++mi) af[mi] = *(const bf16x8*)&Asm[aro[mi]];
#pragma unroll
    for (int ni = 0; ni < 4; ++ni) {
      b1f[ni] = *(const bf16x8*)&B1sm[bro[ni]];
      b3f[ni] = *(const bf16x8*)&B3sm[bro[ni]];
    }
#pragma unroll
    for (int mi = 0; mi < 4; ++mi)
#pragma unroll
      for (int ni = 0; ni < 4; ++ni) {
        acc1[mi][ni] = __builtin_amdgcn_mfma_f32_16x16x32_bf16(af[mi], b1f[ni], acc1[mi][ni], 0, 0, 0);
        acc3[mi][ni] = __builtin_amdgcn_mfma_f32_16x16x32_bf16(af[mi], b3f[ni], acc3[mi][ni], 0, 0, 0);
      }
  }
  const int off = offsets[e];
#pragma unroll
  for (int mi = 0; mi < 4; ++mi)
#pragma unroll
    for (int r = 0; r < 4; ++r) {
      int row = wm + mi * 16 + quad * 4 + r;
      int grow = rb * 128 + row;
      if (grow < cnt) {
        size_t rowbase = (size_t)(off + grow) * HH + (size_t)nb * 128 + wn;
#pragma unroll
        for (int ni = 0; ni < 4; ++ni) {
          float a = acc1[mi][ni][r], b = acc3[mi][ni][r];
          float h = a / (1.f + __expf(-a)) * b;
          Hbuf[rowbase + ni * 16 + l16] = f2bf(h);
        }
      }
    }
}

__global__ __launch_bounds__(256, 2) void g2s_kernel(
    const short* __restrict__ Hbuf, const float* __restrict__ w2,
    const int* __restrict__ cpad, const int* __restrict__ offsets,
    const int* __restrict__ list_token, const float* __restrict__ list_coef,
    float* __restrict__ out)
{
  const int e = blockIdx.z, rb = blockIdx.y, nb = blockIdx.x;
  const int cnt = cpad[e * 16];
  if (rb * 128 >= cnt) return;
  __shared__ short Asm[128 * 40];
  __shared__ short Bsm[128 * 40];
  const int tid = threadIdx.x, lane = tid & 63, wv = tid >> 6;
  const int wm = (wv >> 1) * 64, wn = (wv & 1) * 64;
  const int quad = lane >> 4, l16 = lane & 15;
  floatx4 acc[4][4] = {{{0.f}}};
  const int ar = tid >> 3, ak = (tid & 7) * 4;
  const int bp = tid & 63, bq = tid >> 6;
  const int bswz = (bq ^ ((bp >> 2) & 3)) * 8;
  const int bo0 = (2 * bp) * 40 + bswz, bo1 = bo0 + 40;
  int aro[4], bro[4];
#pragma unroll
  for (int mi = 0; mi < 4; ++mi) aro[mi] = (wm + mi * 16 + l16) * 40 + quad * 8;
#pragma unroll
  for (int ni = 0; ni < 4; ++ni) {
    int nl = wn + ni * 16 + l16;
    bro[ni] = nl * 40 + ((quad ^ ((nl >> 3) & 3)) * 8);
  }
  const int off = offsets[e];
  size_t hrow[4];
#pragma unroll
  for (int i = 0; i < 4; ++i) {
    int gr = rb * 128 + ar + 32 * i;
    int cg = (gr < cnt) ? gr : (cnt - 1);
    hrow[i] = (size_t)(off + cg) * HH;
  }
  const float* w2e = w2 + (size_t)e * HH * DD + (size_t)nb * 128;
  for (int k0 = 0; k0 < HH; k0 += 32) {
    __syncthreads();
#pragma unroll
    for (int i = 0; i < 4; ++i) {
      int r = ar + 32 * i;
      short4 sv = *(const short4*)(Hbuf + hrow[i] + k0 + ak);
      *(short4*)&Asm[r * 40 + ak] = sv;
    }
    {
      float2 u[8];
#pragma unroll
      for (int j = 0; j < 8; ++j) u[j] = *(const float2*)(w2e + (size_t)(k0 + bq * 8 + j) * DD + 2 * bp);
      shortx8 p0, p1;
#pragma unroll
      for (int j = 0; j < 8; ++j) { p0[j] = f2bf(u[j].x); p1[j] = f2bf(u[j].y); }
      *(shortx8*)&Bsm[bo0] = p0; *(shortx8*)&Bsm[bo1] = p1;
    }
    __syncthreads();
    bf16x8 af[4], bf[4];
#pragma unroll
    for (int mi = 0; mi < 4; ++mi) af[mi] = *(const bf16x8*)&Asm[aro[mi]];
#pragma unroll
    for (int ni = 0; ni < 4; ++ni) bf[ni] = *(const bf16x8*)&Bsm[bro[ni]];
#pragma unroll
    for (int mi = 0; mi < 4; ++mi)
#pragma unroll
      for (int ni = 0; ni < 4; ++ni)
        acc[mi][ni] = __builtin_amdgcn_mfma_f32_16x16x32_bf16(af[mi], bf[ni], acc[mi][ni], 0, 0, 0);
  }
#pragma unroll
  for (int mi = 0; mi < 4; ++mi)
#pragma unroll
    for (int r = 0; r < 4; ++r) {
      int row = wm + mi * 16 + quad * 4 + r;
      int grow = rb * 128 + row;
      if (grow < cnt) {
        int tokid = list_token[e * TT + grow];
        float coef = list_coef[e * TT + grow];
        float* orow = out + (size_t)tokid * DD + (size_t)nb * 128 + wn;
#pragma unroll
        for (int ni = 0; ni < 4; ++ni)
          atomicAdd(&orow[ni * 16 + l16], coef * acc[mi][ni][r]);
      }
    }
}

extern "C" void kernel_launch(void* const* d_in, const int* in_sizes, int n_in,
                              void* d_out, int out_size, void* d_ws, size_t ws_size,
                              hipStream_t stream)
{
  const float* x  = (const float*)d_in[0];
  const float* rw = (const float*)d_in[1];
  const float* w1 = (const float*)d_in[2];
  const float* w3 = (const float*)d_in[3];
  const float* w2 = (const float*)d_in[4];
  float* out = (float*)d_out;

  char* ws = (char*)d_ws;
  int*   cpad      = (int*)(ws + 0);        // 8 counters, one per 64-B line (512 B)
  float* ppad      = (float*)(ws + 512);    // 8 P accumulators, padded (512 B)
  int*   offsets   = (int*)(ws + 1024);
  int*   list_tok  = (int*)(ws + 4096);                    // E*T ints   (256 KB)
  float* list_coef = (float*)(ws + 4096 + EE * TT * 4);    // E*T floats (256 KB)

  // fast-path layout (bytes): hdr 1MB | W1T 32MB (reused as W2T) | W3T 32MB | XBF 16MB | HBUF
  const size_t OFF_W1T = 1u << 20;
  const size_t OFF_W3T = OFF_W1T + ((size_t)EE * DD * HH * 2);
  const size_t OFF_XBF = OFF_W3T + ((size_t)EE * DD * HH * 2);
  const size_t OFF_HB  = OFF_XBF + ((size_t)TT * DD * 2);
  const size_t NEED    = OFF_HB + ((size_t)(2 * TT + 128) * HH * 2);   // ~145.5 MiB

  hipMemsetAsync(ws, 0, 1024, stream);                                  // cpad + ppad
  hipMemsetAsync(d_out, 0, (size_t)TT * DD * sizeof(float), stream);    // scatter target

  const bool fast = (ws_size >= NEED);
  short* XBF = fast ? (short*)(ws + OFF_XBF) : nullptr;

  router_kernel<<<256, 256, 0, stream>>>(x, rw, cpad, ppad, list_tok, list_coef, XBF);
  aux_kernel<<<1, 64, 0, stream>>>(cpad, ppad, offsets, out + (size_t)TT * DD);

  if (fast) {
    short* W1T = (short*)(ws + OFF_W1T);
    short* W3T = (short*)(ws + OFF_W3T);
    short* HB  = (short*)(ws + OFF_HB);
    convt_kernel<<<dim3(HH / 64, DD / 64, EE), 256, 0, stream>>>(w1, W1T, DD, HH);
    convt_kernel<<<dim3(HH / 64, DD / 64, EE), 256, 0, stream>>>(w3, W3T, DD, HH);
    g1f_kernel<<<dim3(HH / 128, TT / 128, EE), 256, 0, stream>>>(XBF, W1T, W3T, cpad, offsets, list_tok, HB);
    // w2t overwrites W1T region after g1 has consumed it (in-order stream)
    convt_kernel<<<dim3(DD / 64, HH / 64, EE), 256, 0, stream>>>(w2, W1T, HH, DD);
    g2f_kernel<<<dim3(DD / 128, TT / 128, EE), 256, 0, stream>>>(HB, W1T, cpad, offsets, list_tok, list_coef, out);
  } else {
    short* HB = (short*)(ws + (1 << 20));
    g1s_kernel<<<dim3(HH / 128, TT / 128, EE), 256, 0, stream>>>(x, w1, w3, cpad, offsets, list_tok, HB);
    g2s_kernel<<<dim3(DD / 128, TT / 128, EE), 256, 0, stream>>>(HB, w2, cpad, offsets, list_tok, list_coef, out);
  }
}